// Round 11
// baseline (55.211 us; speedup 1.0000x reference)
//
#include <hip/hip_runtime.h>
#include <math.h>

#define C_CLAMP 10000.0f
#define BYP 0.99f
#define LN2F 0.6931471805599453f

constexpr int NL  = 32;   // leaves
constexpr int NI  = 31;   // internal nodes
constexpr int NG  = 15;   // internal nodes above level 1 (nodes 16..30)
constexpr int BLK = 256;

typedef float f4 __attribute__((ext_vector_type(4)));
typedef float f2 __attribute__((ext_vector_type(2)));

// out = exp(log(l) * log(r)) for complex l, r; then nan_to_num + clip.
// Fast path (real-positive operands) unconditional; full complex path behind a
// WAVE-UNIFORM branch (rarely taken).
template<bool HASIM>
__device__ __forceinline__ void eml_op(float lre, float lim, float rre, float rim,
                                       float& ore, float& oim) {
    bool ok = fminf(lre, rre) > 0.0f;
    if constexpr (HASIM)
        ok = ok & (fmaxf(fabsf(lim), fabsf(rim)) == 0.0f);

    float t = __log2f(lre) * __log2f(rre);
    float e = __builtin_amdgcn_exp2f(t * LN2F);   // +inf -> clipped below
    ore = fminf(e, C_CLAMP);
    oim = 0.0f;

    if (__any(!ok)) {                     // wave-uniform skip
        float a = 0.5f * logf(fmaf(lre, lre, lim * lim));
        float b = atan2f(lim, lre);
        float c = 0.5f * logf(fmaf(rre, rre, rim * rim));
        float d = atan2f(rim, rre);
        float tt = a * c - b * d;
        float th = a * d + b * c;
        float ex = expf(tt);
        float re_ = ex * cosf(th);
        float im_ = ex * sinf(th);
        re_ = __builtin_isnan(re_) ? 0.0f : re_;
        im_ = __builtin_isnan(im_) ? 0.0f : im_;
        re_ = fminf(fmaxf(re_, -C_CLAMP), C_CLAMP);
        im_ = fminf(fmaxf(im_, -C_CLAMP), C_CLAMP);
        if (!ok) { ore = re_; oim = im_; }
    }
}

// g4b[node-16] = (sl_eff, oml_eff, sr_eff, omr_eff); bypass pre-folded to (1,0).
template<int NP>
__device__ __forceinline__ void do_level(const f4* g4b, int node0,
                                         const float* ire, const float* iim,
                                         float* ore, float* oim) {
#pragma unroll
    for (int p = 0; p < NP; ++p) {
        f4 gg = g4b[node0 - 16 + p];      // one ds_read_b128, broadcast
        float lre = fmaf(gg.y, ire[2 * p],     gg.x);
        float rre = fmaf(gg.w, ire[2 * p + 1], gg.z);
        float lim = gg.y * iim[2 * p];
        float rim = gg.w * iim[2 * p + 1];
        eml_op<true>(lre, lim, rre, rim, ore[p], oim[p]);
    }
}

// PAIRS=true: interleaved (re,im). PAIRS=false: real part only. Plain (cached) stores.
template<bool PAIRS, int NP>
__device__ __forceinline__ void store_lvl(float* __restrict__ dst, long long sb,
                                          const float* re, const float* im) {
    if constexpr (PAIRS) {
        float* p = dst + sb * (2 * NP);
        if constexpr (NP >= 2) {
#pragma unroll
            for (int q = 0; q < NP; q += 2)
                *reinterpret_cast<f4*>(p + 2 * q) = f4{ re[q], im[q], re[q + 1], im[q + 1] };
        } else {
            *reinterpret_cast<f2*>(p) = f2{ re[0], im[0] };
        }
    } else {
        float* p = dst + sb * NP;
        if constexpr (NP >= 4) {
#pragma unroll
            for (int q = 0; q < NP; q += 4)
                *reinterpret_cast<f4*>(p + q) = f4{ re[q], re[q + 1], re[q + 2], re[q + 3] };
        } else if constexpr (NP == 2) {
            *reinterpret_cast<f2*>(p) = f2{ re[0], re[1] };
        } else {
            p[0] = re[0];
        }
    }
}

template<bool PAIRS>
__global__ __launch_bounds__(BLK, 4) void eml_tree_kernel(
    const float* __restrict__ x, const float* __restrict__ y,
    const float* __restrict__ leaf_logits, const float* __restrict__ blend_logits,
    float* __restrict__ o_pred, float* __restrict__ o_leaf, float* __restrict__ o_gate,
    float* __restrict__ o_l1, float* __restrict__ o_l2, float* __restrict__ o_l3,
    float* __restrict__ o_l4, float* __restrict__ o_l5,
    int B, int blocksPerS, int kPerS)
{
    __shared__ f4    eff4[NL];      // per-leaf (A, Bx, By, 0): level-1 gate folded into softmax
    __shared__ f4    g4b[NG];       // nodes 16..30: (sl_eff, oml, sr_eff, omr), bypass folded
    __shared__ float graw[NI * 2];  // raw sigmoids for gate_probs output
    // store-transpose staging (real mode): bank = (e + tid) % 32, conflict-free writes
    __shared__ float st1[16][BLK + 1];
    __shared__ float st2[8][BLK + 1];

    const int s   = blockIdx.x / kPerS;
    const int j   = blockIdx.x - s * kPerS;
    const int tid = threadIdx.x;

    if (tid < NL) {
        // leaf thread: softmax + own level-1 gate side, fold into (A,Bx,By)
        const float* p = leaf_logits + (s * NL + tid) * 3;
        float a0 = p[0], a1 = p[1], a2 = p[2];
        float m  = fmaxf(a0, fmaxf(a1, a2));
        float e0 = expf(a0 - m), e1 = expf(a1 - m), e2 = expf(a2 - m);
        float inv = 1.0f / (e0 + e1 + e2);
        float w0 = e0 * inv, w1 = e1 * inv, w2 = e2 * inv;

        float sg = 1.0f / (1.0f + expf(-blend_logits[s * NI * 2 + tid])); // node tid/2, side tid&1
        graw[tid] = sg;
        if (sg > BYP) {
            eff4[tid] = f4{ 1.0f, 0.0f, 0.0f, 0.0f };
        } else {
            float om = 1.0f - sg;
            eff4[tid] = f4{ fmaf(om, w0, sg), om * w1, om * w2, 0.0f };
        }
        if (j == 0) {
            float* q = o_leaf + s * NL * 3 + tid * 3;
            q[0] = w0; q[1] = w1; q[2] = w2;
        }
    } else if (tid >= 64 && tid < 64 + NG) {
        int i = tid - 64;                 // node 16+i
        const float* p = blend_logits + s * NI * 2 + (16 + i) * 2;
        float sl = 1.0f / (1.0f + expf(-p[0]));
        float sr = 1.0f / (1.0f + expf(-p[1]));
        graw[(16 + i) * 2]     = sl;
        graw[(16 + i) * 2 + 1] = sr;
        bool bl = sl > BYP, br = sr > BYP;
        g4b[i] = f4{ bl ? 1.0f : sl, bl ? 0.0f : (1.0f - sl),
                     br ? 1.0f : sr, br ? 0.0f : (1.0f - sr) };
    }
    __syncthreads();

    if (j == 0 && tid >= 128 && tid < 128 + NI * 2)
        o_gate[s * NI * 2 + (tid - 128)] = graw[tid - 128];

    const long long sBase = (long long)s * B;

    // Persistent loop: this block handles chunks j, j+kPerS, ... (uniform count
    // when kPerS divides blocksPerS -> zero tail; tables built once).
    for (int chunk = j; chunk < blocksPerS; chunk += kPerS) {
        const int b = chunk * BLK + tid;
        const bool active = b < B;
        const float xv = active ? x[b] : 0.0f;
        const float yv = active ? y[b] : 0.0f;
        const long long sb = sBase + b;

        if (active) {
            // Levels 1+2 fused (rolling 4-wide l1 buffer keeps VGPR pressure low).
            float r2[8], i2[8];
            float b1r[4], b1i[4];
#pragma unroll
            for (int q = 0; q < 8; ++q) {
                const int h0 = (q & 1) * 2;
#pragma unroll
                for (int h = 0; h < 2; ++h) {
                    const int p = 2 * q + h;      // l1 node index
                    f4 ea = eff4[2 * p];
                    f4 eb = eff4[2 * p + 1];
                    float lre = fmaf(ea.z, yv, fmaf(ea.y, xv, ea.x));
                    float rre = fmaf(eb.z, yv, fmaf(eb.y, xv, eb.x));
                    eml_op<false>(lre, 0.0f, rre, 0.0f, b1r[h0 + h], b1i[h0 + h]);
                    if constexpr (!PAIRS) st1[p][tid] = b1r[h0 + h];
                }
                {   // l2 node q (tree node 16+q)
                    f4 gg = g4b[q];
                    float lre = fmaf(gg.y, b1r[h0],     gg.x);
                    float rre = fmaf(gg.w, b1r[h0 + 1], gg.z);
                    float lim = gg.y * b1i[h0];
                    float rim = gg.w * b1i[h0 + 1];
                    eml_op<true>(lre, lim, rre, rim, r2[q], i2[q]);
                    if constexpr (!PAIRS) st2[q][tid] = r2[q];
                }
                if (PAIRS && (q & 1)) {           // flush l1 nodes 2q-2 .. 2q+1
                    float* pp = o_l1 + sb * 32 + (q - 1) * 4;
                    *reinterpret_cast<f4*>(pp)     = f4{ b1r[0], b1i[0], b1r[1], b1i[1] };
                    *reinterpret_cast<f4*>(pp + 4) = f4{ b1r[2], b1i[2], b1r[3], b1i[3] };
                }
            }
            if constexpr (PAIRS) store_lvl<PAIRS, 8>(o_l2, sb, r2, i2);

            float r3[4], i3[4];
            do_level<4>(g4b, 24, r2, i2, r3, i3);
            store_lvl<PAIRS, 4>(o_l3, sb, r3, i3);

            float r4[2], i4[2];
            do_level<2>(g4b, 28, r3, i3, r4, i4);
            store_lvl<PAIRS, 2>(o_l4, sb, r4, i4);

            float r5[1], i5[1];
            do_level<1>(g4b, 30, r4, i4, r5, i5);
            store_lvl<PAIRS, 1>(o_l5, sb, r5, i5);
            store_lvl<PAIRS, 1>(o_pred, sb, r5, i5);
        }

        if constexpr (!PAIRS) {
            __syncthreads();
            // Cooperative, fully lane-contiguous f4 stores of the block's l1/l2 regions.
            const long long b0 = sBase + (long long)chunk * BLK;
            float* dst1 = o_l1 + b0 * 16;     // BLK*16 floats = BLK*4 f4
#pragma unroll
            for (int k = 0; k < 4; ++k) {
                int m  = tid + BLK * k;
                int bl = m >> 2, e0 = (m & 3) << 2;
                if (chunk * BLK + bl < B) {
                    f4 v = { st1[e0][bl], st1[e0 + 1][bl], st1[e0 + 2][bl], st1[e0 + 3][bl] };
                    *reinterpret_cast<f4*>(dst1 + 4 * (long long)m) = v;
                }
            }
            float* dst2 = o_l2 + b0 * 8;      // BLK*8 floats = BLK*2 f4
#pragma unroll
            for (int k = 0; k < 2; ++k) {
                int m  = tid + BLK * k;
                int bl = m >> 1, e0 = (m & 1) << 2;
                if (chunk * BLK + bl < B) {
                    f4 v = { st2[e0][bl], st2[e0 + 1][bl], st2[e0 + 2][bl], st2[e0 + 3][bl] };
                    *reinterpret_cast<f4*>(dst2 + 4 * (long long)m) = v;
                }
            }
            __syncthreads();   // WAR: next iteration overwrites st1/st2
        }
    }
}

extern "C" void kernel_launch(void* const* d_in, const int* in_sizes, int n_in,
                              void* d_out, int out_size, void* d_ws, size_t ws_size,
                              hipStream_t stream) {
    const float* x     = (const float*)d_in[0];
    const float* y     = (const float*)d_in[1];
    const float* leaf  = (const float*)d_in[2];
    const float* blend = (const float*)d_in[3];

    const int B = in_sizes[0];
    const int S = in_sizes[2] / (NL * 3);

    float* out = (float*)d_out;
    const long long SB = (long long)S * B;
    const long long size_pairs = SB * 64 + (long long)S * (NL * 3 + NI * 2);

    const int blocksPerS = (B + BLK - 1) / BLK;

    // Persistent decomposition: kPerS = largest divisor of blocksPerS with
    // S*kPerS <= ~1024 (4 blocks/CU, fully resident, zero tail). Fallback: all.
    int target = 1024 / (S > 0 ? S : 1);
    if (target < 1) target = 1;
    int kPerS = blocksPerS;
    if (blocksPerS > target) {
        kPerS = 1;
        for (int d = target; d >= 1; --d)
            if (blocksPerS % d == 0) { kPerS = d; break; }
    }

    dim3 grid(S * kPerS), block(BLK);

    if ((long long)out_size >= size_pairs) {
        // complex64 stored as interleaved float pairs
        float* o_pred = out;                               // SB*2
        float* o_leaf = o_pred + SB * 2;                   // S*96
        float* o_gate = o_leaf + (long long)S * NL * 3;    // S*62
        float* o_l1   = o_gate + (long long)S * NI * 2;    // SB*32
        float* o_l2   = o_l1 + SB * 32;
        float* o_l3   = o_l2 + SB * 16;
        float* o_l4   = o_l3 + SB * 8;
        float* o_l5   = o_l4 + SB * 4;
        hipLaunchKernelGGL((eml_tree_kernel<true>), grid, block, 0, stream,
                           x, y, leaf, blend,
                           o_pred, o_leaf, o_gate, o_l1, o_l2, o_l3, o_l4, o_l5,
                           B, blocksPerS, kPerS);
    } else {
        // real parts only (harness flattens complex64 outputs as float32 real)
        float* o_pred = out;                               // SB
        float* o_leaf = o_pred + SB;                       // S*96
        float* o_gate = o_leaf + (long long)S * NL * 3;    // S*62
        float* o_l1   = o_gate + (long long)S * NI * 2;    // SB*16
        float* o_l2   = o_l1 + SB * 16;
        float* o_l3   = o_l2 + SB * 8;
        float* o_l4   = o_l3 + SB * 4;
        float* o_l5   = o_l4 + SB * 2;
        hipLaunchKernelGGL((eml_tree_kernel<false>), grid, block, 0, stream,
                           x, y, leaf, blend,
                           o_pred, o_leaf, o_gate, o_l1, o_l2, o_l3, o_l4, o_l5,
                           B, blocksPerS, kPerS);
    }
}

// Round 12
// 48.228 us; speedup vs baseline: 1.1448x; 1.1448x over previous
//
#include <hip/hip_runtime.h>
#include <math.h>

#define C_CLAMP 10000.0f
#define BYP 0.99f
#define LN2F 0.6931471805599453f

constexpr int NL  = 32;   // leaves
constexpr int NI  = 31;   // internal nodes
constexpr int NG  = 15;   // internal nodes above level 1 (nodes 16..30)
constexpr int BLK = 128;  // smaller blocks -> shorter end-of-grid drain tail

typedef float f4 __attribute__((ext_vector_type(4)));
typedef float f2 __attribute__((ext_vector_type(2)));

// out = exp(log(l) * log(r)) for complex l, r; then nan_to_num + clip.
// Fast path (real-positive operands) unconditional; full complex path behind a
// WAVE-UNIFORM branch (rarely taken).
template<bool HASIM>
__device__ __forceinline__ void eml_op(float lre, float lim, float rre, float rim,
                                       float& ore, float& oim) {
    bool ok = fminf(lre, rre) > 0.0f;
    if constexpr (HASIM)
        ok = ok & (fmaxf(fabsf(lim), fabsf(rim)) == 0.0f);

    float t = __log2f(lre) * __log2f(rre);
    float e = __builtin_amdgcn_exp2f(t * LN2F);   // +inf -> clipped below
    ore = fminf(e, C_CLAMP);
    oim = 0.0f;

    if (__any(!ok)) {                     // wave-uniform skip
        float a = 0.5f * logf(fmaf(lre, lre, lim * lim));
        float b = atan2f(lim, lre);
        float c = 0.5f * logf(fmaf(rre, rre, rim * rim));
        float d = atan2f(rim, rre);
        float tt = a * c - b * d;
        float th = a * d + b * c;
        float ex = expf(tt);
        float re_ = ex * cosf(th);
        float im_ = ex * sinf(th);
        re_ = __builtin_isnan(re_) ? 0.0f : re_;
        im_ = __builtin_isnan(im_) ? 0.0f : im_;
        re_ = fminf(fmaxf(re_, -C_CLAMP), C_CLAMP);
        im_ = fminf(fmaxf(im_, -C_CLAMP), C_CLAMP);
        if (!ok) { ore = re_; oim = im_; }
    }
}

// g4b[node-16] = (sl_eff, oml_eff, sr_eff, omr_eff); bypass pre-folded to (1,0).
template<int NP>
__device__ __forceinline__ void do_level(const f4* g4b, int node0,
                                         const float* ire, const float* iim,
                                         float* ore, float* oim) {
#pragma unroll
    for (int p = 0; p < NP; ++p) {
        f4 gg = g4b[node0 - 16 + p];      // one ds_read_b128, broadcast
        float lre = fmaf(gg.y, ire[2 * p],     gg.x);
        float rre = fmaf(gg.w, ire[2 * p + 1], gg.z);
        float lim = gg.y * iim[2 * p];
        float rim = gg.w * iim[2 * p + 1];
        eml_op<true>(lre, lim, rre, rim, ore[p], oim[p]);
    }
}

// PAIRS=true: interleaved (re,im). PAIRS=false: real part only. Plain (cached) stores.
template<bool PAIRS, int NP>
__device__ __forceinline__ void store_lvl(float* __restrict__ dst, long long sb,
                                          const float* re, const float* im) {
    if constexpr (PAIRS) {
        float* p = dst + sb * (2 * NP);
        if constexpr (NP >= 2) {
#pragma unroll
            for (int q = 0; q < NP; q += 2)
                *reinterpret_cast<f4*>(p + 2 * q) = f4{ re[q], im[q], re[q + 1], im[q + 1] };
        } else {
            *reinterpret_cast<f2*>(p) = f2{ re[0], im[0] };
        }
    } else {
        float* p = dst + sb * NP;
        if constexpr (NP >= 4) {
#pragma unroll
            for (int q = 0; q < NP; q += 4)
                *reinterpret_cast<f4*>(p + q) = f4{ re[q], re[q + 1], re[q + 2], re[q + 3] };
        } else if constexpr (NP == 2) {
            *reinterpret_cast<f2*>(p) = f2{ re[0], re[1] };
        } else {
            p[0] = re[0];
        }
    }
}

template<bool PAIRS>
__global__ __launch_bounds__(BLK, 6) void eml_tree_kernel(
    const float* __restrict__ x, const float* __restrict__ y,
    const float* __restrict__ leaf_logits, const float* __restrict__ blend_logits,
    float* __restrict__ o_pred, float* __restrict__ o_leaf, float* __restrict__ o_gate,
    float* __restrict__ o_l1, float* __restrict__ o_l2, float* __restrict__ o_l3,
    float* __restrict__ o_l4, float* __restrict__ o_l5,
    int B, int blocksPerS)
{
    __shared__ f4    eff4[NL];      // per-leaf (A, Bx, By, 0): level-1 gate folded into softmax
    __shared__ f4    g4b[NG];       // nodes 16..30: (sl_eff, oml, sr_eff, omr), bypass folded
    __shared__ float graw[NI * 2];  // raw sigmoids for gate_probs output
    // store-transpose staging (real mode): bank = (e + tid) % 32, conflict-free
    __shared__ float st1[16][BLK + 1];
    __shared__ float st2[8][BLK + 1];

    const int bid   = blockIdx.x;
    const int s     = bid / blocksPerS;
    const int chunk = bid - s * blocksPerS;
    const int tid   = threadIdx.x;

    if (tid < NL) {
        // leaf thread: softmax + own level-1 gate side, fold into (A,Bx,By)
        const float* p = leaf_logits + (s * NL + tid) * 3;
        float a0 = p[0], a1 = p[1], a2 = p[2];
        float m  = fmaxf(a0, fmaxf(a1, a2));
        float e0 = expf(a0 - m), e1 = expf(a1 - m), e2 = expf(a2 - m);
        float inv = 1.0f / (e0 + e1 + e2);
        float w0 = e0 * inv, w1 = e1 * inv, w2 = e2 * inv;

        float sg = 1.0f / (1.0f + expf(-blend_logits[s * NI * 2 + tid])); // node tid/2, side tid&1
        graw[tid] = sg;
        if (sg > BYP) {
            eff4[tid] = f4{ 1.0f, 0.0f, 0.0f, 0.0f };
        } else {
            float om = 1.0f - sg;
            eff4[tid] = f4{ fmaf(om, w0, sg), om * w1, om * w2, 0.0f };
        }
        if (chunk == 0) {
            float* q = o_leaf + s * NL * 3 + tid * 3;
            q[0] = w0; q[1] = w1; q[2] = w2;
        }
    } else if (tid >= 64 && tid < 64 + NG) {
        int i = tid - 64;                 // node 16+i
        const float* p = blend_logits + s * NI * 2 + (16 + i) * 2;
        float sl = 1.0f / (1.0f + expf(-p[0]));
        float sr = 1.0f / (1.0f + expf(-p[1]));
        graw[(16 + i) * 2]     = sl;
        graw[(16 + i) * 2 + 1] = sr;
        bool bl = sl > BYP, br = sr > BYP;
        g4b[i] = f4{ bl ? 1.0f : sl, bl ? 0.0f : (1.0f - sl),
                     br ? 1.0f : sr, br ? 0.0f : (1.0f - sr) };
    }
    __syncthreads();

    if (chunk == 0) {
        for (int i = tid; i < NI * 2; i += BLK)   // BLK-agnostic gate_probs writeout
            o_gate[s * NI * 2 + i] = graw[i];
    }

    const int b = chunk * BLK + tid;
    const bool active = b < B;
    const float xv = active ? x[b] : 0.0f;
    const float yv = active ? y[b] : 0.0f;
    const long long sb = (long long)s * B + b;

    if (active) {
        // Levels 1+2 fused (rolling 4-wide l1 buffer keeps VGPR pressure low).
        float r2[8], i2[8];
        float b1r[4], b1i[4];
#pragma unroll
        for (int q = 0; q < 8; ++q) {
            const int h0 = (q & 1) * 2;
#pragma unroll
            for (int h = 0; h < 2; ++h) {
                const int p = 2 * q + h;      // l1 node index
                f4 ea = eff4[2 * p];
                f4 eb = eff4[2 * p + 1];
                float lre = fmaf(ea.z, yv, fmaf(ea.y, xv, ea.x));
                float rre = fmaf(eb.z, yv, fmaf(eb.y, xv, eb.x));
                eml_op<false>(lre, 0.0f, rre, 0.0f, b1r[h0 + h], b1i[h0 + h]);
                if constexpr (!PAIRS) st1[p][tid] = b1r[h0 + h];
            }
            {   // l2 node q (tree node 16+q)
                f4 gg = g4b[q];
                float lre = fmaf(gg.y, b1r[h0],     gg.x);
                float rre = fmaf(gg.w, b1r[h0 + 1], gg.z);
                float lim = gg.y * b1i[h0];
                float rim = gg.w * b1i[h0 + 1];
                eml_op<true>(lre, lim, rre, rim, r2[q], i2[q]);
                if constexpr (!PAIRS) st2[q][tid] = r2[q];
            }
            if (PAIRS && (q & 1)) {           // flush l1 nodes 2q-2 .. 2q+1
                float* pp = o_l1 + sb * 32 + (q - 1) * 4;
                *reinterpret_cast<f4*>(pp)     = f4{ b1r[0], b1i[0], b1r[1], b1i[1] };
                *reinterpret_cast<f4*>(pp + 4) = f4{ b1r[2], b1i[2], b1r[3], b1i[3] };
            }
        }
        if constexpr (PAIRS) store_lvl<PAIRS, 8>(o_l2, sb, r2, i2);

        float r3[4], i3[4];
        do_level<4>(g4b, 24, r2, i2, r3, i3);
        store_lvl<PAIRS, 4>(o_l3, sb, r3, i3);

        float r4[2], i4[2];
        do_level<2>(g4b, 28, r3, i3, r4, i4);
        store_lvl<PAIRS, 2>(o_l4, sb, r4, i4);

        float r5[1], i5[1];
        do_level<1>(g4b, 30, r4, i4, r5, i5);
        store_lvl<PAIRS, 1>(o_l5, sb, r5, i5);
        store_lvl<PAIRS, 1>(o_pred, sb, r5, i5);
    }

    if constexpr (!PAIRS) {
        __syncthreads();
        // Cooperative, fully lane-contiguous f4 stores of the block's l1/l2 regions.
        const long long b0 = (long long)s * B + (long long)chunk * BLK;
        float* dst1 = o_l1 + b0 * 16;     // BLK*16 floats = BLK*4 f4
#pragma unroll
        for (int k = 0; k < 4; ++k) {
            int m  = tid + BLK * k;
            int bl = m >> 2, e0 = (m & 3) << 2;
            if (chunk * BLK + bl < B) {
                f4 v = { st1[e0][bl], st1[e0 + 1][bl], st1[e0 + 2][bl], st1[e0 + 3][bl] };
                *reinterpret_cast<f4*>(dst1 + 4 * (long long)m) = v;
            }
        }
        float* dst2 = o_l2 + b0 * 8;      // BLK*8 floats = BLK*2 f4
#pragma unroll
        for (int k = 0; k < 2; ++k) {
            int m  = tid + BLK * k;
            int bl = m >> 1, e0 = (m & 1) << 2;
            if (chunk * BLK + bl < B) {
                f4 v = { st2[e0][bl], st2[e0 + 1][bl], st2[e0 + 2][bl], st2[e0 + 3][bl] };
                *reinterpret_cast<f4*>(dst2 + 4 * (long long)m) = v;
            }
        }
    }
}

extern "C" void kernel_launch(void* const* d_in, const int* in_sizes, int n_in,
                              void* d_out, int out_size, void* d_ws, size_t ws_size,
                              hipStream_t stream) {
    const float* x     = (const float*)d_in[0];
    const float* y     = (const float*)d_in[1];
    const float* leaf  = (const float*)d_in[2];
    const float* blend = (const float*)d_in[3];

    const int B = in_sizes[0];
    const int S = in_sizes[2] / (NL * 3);

    float* out = (float*)d_out;
    const long long SB = (long long)S * B;
    const long long size_pairs = SB * 64 + (long long)S * (NL * 3 + NI * 2);

    const int blocksPerS = (B + BLK - 1) / BLK;
    dim3 grid(S * blocksPerS), block(BLK);

    if ((long long)out_size >= size_pairs) {
        // complex64 stored as interleaved float pairs
        float* o_pred = out;                               // SB*2
        float* o_leaf = o_pred + SB * 2;                   // S*96
        float* o_gate = o_leaf + (long long)S * NL * 3;    // S*62
        float* o_l1   = o_gate + (long long)S * NI * 2;    // SB*32
        float* o_l2   = o_l1 + SB * 32;
        float* o_l3   = o_l2 + SB * 16;
        float* o_l4   = o_l3 + SB * 8;
        float* o_l5   = o_l4 + SB * 4;
        hipLaunchKernelGGL((eml_tree_kernel<true>), grid, block, 0, stream,
                           x, y, leaf, blend,
                           o_pred, o_leaf, o_gate, o_l1, o_l2, o_l3, o_l4, o_l5,
                           B, blocksPerS);
    } else {
        // real parts only (harness flattens complex64 outputs as float32 real)
        float* o_pred = out;                               // SB
        float* o_leaf = o_pred + SB;                       // S*96
        float* o_gate = o_leaf + (long long)S * NL * 3;    // S*62
        float* o_l1   = o_gate + (long long)S * NI * 2;    // SB*16
        float* o_l2   = o_l1 + SB * 16;
        float* o_l3   = o_l2 + SB * 8;
        float* o_l4   = o_l3 + SB * 4;
        float* o_l5   = o_l4 + SB * 2;
        hipLaunchKernelGGL((eml_tree_kernel<false>), grid, block, 0, stream,
                           x, y, leaf, blend,
                           o_pred, o_leaf, o_gate, o_l1, o_l2, o_l3, o_l4, o_l5,
                           B, blocksPerS);
    }
}

// Round 13
// 47.032 us; speedup vs baseline: 1.1739x; 1.0254x over previous
//
#include <hip/hip_runtime.h>
#include <math.h>

#define C_CLAMP 10000.0f
#define BYP 0.99f
#define LN2F 0.6931471805599453f

constexpr int NL  = 32;   // leaves
constexpr int NI  = 31;   // internal nodes
constexpr int NG  = 15;   // internal nodes above level 1 (nodes 16..30)
constexpr int BLK = 256;

typedef float f4 __attribute__((ext_vector_type(4)));
typedef float f2 __attribute__((ext_vector_type(2)));

// out = exp(log(l) * log(r)) for complex l, r; then nan_to_num + clip.
// Fast path (real-positive operands) unconditional; full complex path behind a
// WAVE-UNIFORM branch (rarely taken).
template<bool HASIM>
__device__ __forceinline__ void eml_op(float lre, float lim, float rre, float rim,
                                       float& ore, float& oim) {
    bool ok = fminf(lre, rre) > 0.0f;
    if constexpr (HASIM)
        ok = ok & (fmaxf(fabsf(lim), fabsf(rim)) == 0.0f);

    float t = __log2f(lre) * __log2f(rre);
    float e = __builtin_amdgcn_exp2f(t * LN2F);   // +inf -> clipped below
    ore = fminf(e, C_CLAMP);
    oim = 0.0f;

    if (__any(!ok)) {                     // wave-uniform skip
        float a = 0.5f * logf(fmaf(lre, lre, lim * lim));
        float b = atan2f(lim, lre);
        float c = 0.5f * logf(fmaf(rre, rre, rim * rim));
        float d = atan2f(rim, rre);
        float tt = a * c - b * d;
        float th = a * d + b * c;
        float ex = expf(tt);
        float re_ = ex * cosf(th);
        float im_ = ex * sinf(th);
        re_ = __builtin_isnan(re_) ? 0.0f : re_;
        im_ = __builtin_isnan(im_) ? 0.0f : im_;
        re_ = fminf(fmaxf(re_, -C_CLAMP), C_CLAMP);
        im_ = fminf(fmaxf(im_, -C_CLAMP), C_CLAMP);
        if (!ok) { ore = re_; oim = im_; }
    }
}

// g4b[node-16] = (sl_eff, oml_eff, sr_eff, omr_eff); bypass pre-folded to (1,0).
template<int NP>
__device__ __forceinline__ void do_level(const f4* g4b, int node0,
                                         const float* ire, const float* iim,
                                         float* ore, float* oim) {
#pragma unroll
    for (int p = 0; p < NP; ++p) {
        f4 gg = g4b[node0 - 16 + p];      // one ds_read_b128, broadcast
        float lre = fmaf(gg.y, ire[2 * p],     gg.x);
        float rre = fmaf(gg.w, ire[2 * p + 1], gg.z);
        float lim = gg.y * iim[2 * p];
        float rim = gg.w * iim[2 * p + 1];
        eml_op<true>(lre, lim, rre, rim, ore[p], oim[p]);
    }
}

// PAIRS=true: interleaved (re,im). PAIRS=false: real part only. Plain (cached) stores.
template<bool PAIRS, int NP>
__device__ __forceinline__ void store_lvl(float* __restrict__ dst, long long sb,
                                          const float* re, const float* im) {
    if constexpr (PAIRS) {
        float* p = dst + sb * (2 * NP);
        if constexpr (NP >= 2) {
#pragma unroll
            for (int q = 0; q < NP; q += 2)
                *reinterpret_cast<f4*>(p + 2 * q) = f4{ re[q], im[q], re[q + 1], im[q + 1] };
        } else {
            *reinterpret_cast<f2*>(p) = f2{ re[0], im[0] };
        }
    } else {
        float* p = dst + sb * NP;
        if constexpr (NP >= 4) {
#pragma unroll
            for (int q = 0; q < NP; q += 4)
                *reinterpret_cast<f4*>(p + q) = f4{ re[q], re[q + 1], re[q + 2], re[q + 3] };
        } else if constexpr (NP == 2) {
            *reinterpret_cast<f2*>(p) = f2{ re[0], re[1] };
        } else {
            p[0] = re[0];
        }
    }
}

template<bool PAIRS>
__global__ __launch_bounds__(BLK, 6) void eml_tree_kernel(
    const float* __restrict__ x, const float* __restrict__ y,
    const float* __restrict__ leaf_logits, const float* __restrict__ blend_logits,
    float* __restrict__ o_pred, float* __restrict__ o_leaf, float* __restrict__ o_gate,
    float* __restrict__ o_l1, float* __restrict__ o_l2, float* __restrict__ o_l3,
    float* __restrict__ o_l4, float* __restrict__ o_l5,
    int B, int blocksPerS)
{
    __shared__ f4    eff4[NL];      // per-leaf (A, Bx, By, 0): level-1 gate folded into softmax
    __shared__ f4    g4b[NG];       // nodes 16..30: (sl_eff, oml, sr_eff, omr), bypass folded
    __shared__ float graw[NI * 2];  // raw sigmoids for gate_probs output
    // store-transpose staging (real mode): bank = (e + tid) % 32, conflict-free writes
    __shared__ float st1[16][BLK + 1];
    __shared__ float st2[8][BLK + 1];

    const int bid   = blockIdx.x;
    const int s     = bid / blocksPerS;
    const int chunk = bid - s * blocksPerS;
    const int tid   = threadIdx.x;

    if (tid < NL) {
        // leaf thread: softmax + own level-1 gate side, fold into (A,Bx,By)
        const float* p = leaf_logits + (s * NL + tid) * 3;
        float a0 = p[0], a1 = p[1], a2 = p[2];
        float m  = fmaxf(a0, fmaxf(a1, a2));
        float e0 = expf(a0 - m), e1 = expf(a1 - m), e2 = expf(a2 - m);
        float inv = 1.0f / (e0 + e1 + e2);
        float w0 = e0 * inv, w1 = e1 * inv, w2 = e2 * inv;

        float sg = 1.0f / (1.0f + expf(-blend_logits[s * NI * 2 + tid])); // node tid/2, side tid&1
        graw[tid] = sg;
        if (sg > BYP) {
            eff4[tid] = f4{ 1.0f, 0.0f, 0.0f, 0.0f };
        } else {
            float om = 1.0f - sg;
            eff4[tid] = f4{ fmaf(om, w0, sg), om * w1, om * w2, 0.0f };
        }
        if (chunk == 0) {
            float* q = o_leaf + s * NL * 3 + tid * 3;
            q[0] = w0; q[1] = w1; q[2] = w2;
        }
    } else if (tid >= 64 && tid < 64 + NG) {
        int i = tid - 64;                 // node 16+i
        const float* p = blend_logits + s * NI * 2 + (16 + i) * 2;
        float sl = 1.0f / (1.0f + expf(-p[0]));
        float sr = 1.0f / (1.0f + expf(-p[1]));
        graw[(16 + i) * 2]     = sl;
        graw[(16 + i) * 2 + 1] = sr;
        bool bl = sl > BYP, br = sr > BYP;
        g4b[i] = f4{ bl ? 1.0f : sl, bl ? 0.0f : (1.0f - sl),
                     br ? 1.0f : sr, br ? 0.0f : (1.0f - sr) };
    }
    __syncthreads();

    if (chunk == 0 && tid >= 128 && tid < 128 + NI * 2)
        o_gate[s * NI * 2 + (tid - 128)] = graw[tid - 128];

    const int b = chunk * BLK + tid;
    const bool active = b < B;
    const float xv = active ? x[b] : 0.0f;
    const float yv = active ? y[b] : 0.0f;
    const long long sb = (long long)s * B + b;

    if (active) {
        // Levels 1+2 fused (rolling 4-wide l1 buffer keeps VGPR pressure low).
        float r2[8], i2[8];
        float b1r[4], b1i[4];
#pragma unroll
        for (int q = 0; q < 8; ++q) {
            const int h0 = (q & 1) * 2;
#pragma unroll
            for (int h = 0; h < 2; ++h) {
                const int p = 2 * q + h;      // l1 node index
                f4 ea = eff4[2 * p];
                f4 eb = eff4[2 * p + 1];
                float lre = fmaf(ea.z, yv, fmaf(ea.y, xv, ea.x));
                float rre = fmaf(eb.z, yv, fmaf(eb.y, xv, eb.x));
                eml_op<false>(lre, 0.0f, rre, 0.0f, b1r[h0 + h], b1i[h0 + h]);
                if constexpr (!PAIRS) st1[p][tid] = b1r[h0 + h];
            }
            {   // l2 node q (tree node 16+q)
                f4 gg = g4b[q];
                float lre = fmaf(gg.y, b1r[h0],     gg.x);
                float rre = fmaf(gg.w, b1r[h0 + 1], gg.z);
                float lim = gg.y * b1i[h0];
                float rim = gg.w * b1i[h0 + 1];
                eml_op<true>(lre, lim, rre, rim, r2[q], i2[q]);
                if constexpr (!PAIRS) st2[q][tid] = r2[q];
            }
            if (PAIRS && (q & 1)) {           // flush l1 nodes 2q-2 .. 2q+1
                float* pp = o_l1 + sb * 32 + (q - 1) * 4;
                *reinterpret_cast<f4*>(pp)     = f4{ b1r[0], b1i[0], b1r[1], b1i[1] };
                *reinterpret_cast<f4*>(pp + 4) = f4{ b1r[2], b1i[2], b1r[3], b1i[3] };
            }
        }
        if constexpr (PAIRS) store_lvl<PAIRS, 8>(o_l2, sb, r2, i2);

        float r3[4], i3[4];
        do_level<4>(g4b, 24, r2, i2, r3, i3);
        store_lvl<PAIRS, 4>(o_l3, sb, r3, i3);

        float r4[2], i4[2];
        do_level<2>(g4b, 28, r3, i3, r4, i4);
        store_lvl<PAIRS, 2>(o_l4, sb, r4, i4);

        float r5[1], i5[1];
        do_level<1>(g4b, 30, r4, i4, r5, i5);
        store_lvl<PAIRS, 1>(o_l5, sb, r5, i5);
        store_lvl<PAIRS, 1>(o_pred, sb, r5, i5);
    }

    if constexpr (!PAIRS) {
        __syncthreads();
        // Cooperative, fully lane-contiguous f4 stores of the block's l1/l2 regions.
        const long long b0 = (long long)s * B + (long long)chunk * BLK;
        float* dst1 = o_l1 + b0 * 16;     // BLK*16 floats = BLK*4 f4
#pragma unroll
        for (int k = 0; k < 4; ++k) {
            int m  = tid + BLK * k;
            int bl = m >> 2, e0 = (m & 3) << 2;
            if (chunk * BLK + bl < B) {
                f4 v = { st1[e0][bl], st1[e0 + 1][bl], st1[e0 + 2][bl], st1[e0 + 3][bl] };
                *reinterpret_cast<f4*>(dst1 + 4 * (long long)m) = v;
            }
        }
        float* dst2 = o_l2 + b0 * 8;      // BLK*8 floats = BLK*2 f4
#pragma unroll
        for (int k = 0; k < 2; ++k) {
            int m  = tid + BLK * k;
            int bl = m >> 1, e0 = (m & 1) << 2;
            if (chunk * BLK + bl < B) {
                f4 v = { st2[e0][bl], st2[e0 + 1][bl], st2[e0 + 2][bl], st2[e0 + 3][bl] };
                *reinterpret_cast<f4*>(dst2 + 4 * (long long)m) = v;
            }
        }
    }
}

extern "C" void kernel_launch(void* const* d_in, const int* in_sizes, int n_in,
                              void* d_out, int out_size, void* d_ws, size_t ws_size,
                              hipStream_t stream) {
    const float* x     = (const float*)d_in[0];
    const float* y     = (const float*)d_in[1];
    const float* leaf  = (const float*)d_in[2];
    const float* blend = (const float*)d_in[3];

    const int B = in_sizes[0];
    const int S = in_sizes[2] / (NL * 3);

    float* out = (float*)d_out;
    const long long SB = (long long)S * B;
    const long long size_pairs = SB * 64 + (long long)S * (NL * 3 + NI * 2);

    const int blocksPerS = (B + BLK - 1) / BLK;
    dim3 grid(S * blocksPerS), block(BLK);

    if ((long long)out_size >= size_pairs) {
        // complex64 stored as interleaved float pairs
        float* o_pred = out;                               // SB*2
        float* o_leaf = o_pred + SB * 2;                   // S*96
        float* o_gate = o_leaf + (long long)S * NL * 3;    // S*62
        float* o_l1   = o_gate + (long long)S * NI * 2;    // SB*32
        float* o_l2   = o_l1 + SB * 32;
        float* o_l3   = o_l2 + SB * 16;
        float* o_l4   = o_l3 + SB * 8;
        float* o_l5   = o_l4 + SB * 4;
        hipLaunchKernelGGL((eml_tree_kernel<true>), grid, block, 0, stream,
                           x, y, leaf, blend,
                           o_pred, o_leaf, o_gate, o_l1, o_l2, o_l3, o_l4, o_l5,
                           B, blocksPerS);
    } else {
        // real parts only (harness flattens complex64 outputs as float32 real)
        float* o_pred = out;                               // SB
        float* o_leaf = o_pred + SB;                       // S*96
        float* o_gate = o_leaf + (long long)S * NL * 3;    // S*62
        float* o_l1   = o_gate + (long long)S * NI * 2;    // SB*16
        float* o_l2   = o_l1 + SB * 16;
        float* o_l3   = o_l2 + SB * 8;
        float* o_l4   = o_l3 + SB * 4;
        float* o_l5   = o_l4 + SB * 2;
        hipLaunchKernelGGL((eml_tree_kernel<false>), grid, block, 0, stream,
                           x, y, leaf, blend,
                           o_pred, o_leaf, o_gate, o_l1, o_l2, o_l3, o_l4, o_l5,
                           B, blocksPerS);
    }
}